// Round 5
// baseline (431.486 us; speedup 1.0000x reference)
//
#include <hip/hip_runtime.h>
#include <hip/hip_cooperative_groups.h>

namespace cg = cooperative_groups;

#define NGROUPS 16          // G
#define TPG     16          // threads (lanes) per group in the reduce = 16
#define CHUNK   8           // timesteps per chunk (8 -> 2048 chunks = full occupancy)
#define MAXCPB  16          // max chunks owned per block (grid >= 128 always launchable)
#define EPS_F   1e-5f
#define VFLOOR  1e-6f

typedef float v4f __attribute__((ext_vector_type(4)));   // native vec for nontemporal store

__device__ __forceinline__ float sum8(const float4& a, const float4& b) {
    return ((a.x + a.y) + (a.z + a.w)) + ((b.x + b.y) + (b.z + b.w));
}

// Chan/Welford set-union merge: (na,ma,m2a) ∪= (nb,mb,m2b). Commutative.
__device__ __forceinline__ void wmerge(float& na, float& ma, float& m2a,
                                       float nb, float mb, float m2b) {
    if (nb > 0.f) {
        float nn = na + nb;
        float d  = mb - ma;
        float r  = nb / nn;
        ma  = fmaf(d, r, ma);
        m2a = m2a + m2b + d * d * (na * r);
        na  = nn;
    }
}

// ---------------- fused cooperative kernel, full occupancy ----------------
// R3 proved this structure correct at 2 blocks/CU (latency-bound, 169 us).
// This round: CHUNK=8 -> 2048 chunks; occupancy-query-sized grid (runtime-
// verified co-residency -> no deadlock possible) with CPB chunks/block.
// Expected: 8 blocks/CU (VGPR~30 <= 64, LDS 9.4KB <= 20KB) -> CPB=1.
//
// phase 1 (per owned chunk): read x (only HBM read), group means -> s_gm (LDS),
//          chunk Welford aggregate; leaders publish {n,mean,m2} agent-scope.
// grid.sync()
// phase 2-4 (per owned chunk): merge predecessor aggregates (L2), shfl tree,
//          merge prev state, leader 8-step replay -> s_mean/s_rstd, normalize
//          (x re-read = L3 hit, proven R3: FETCH stayed 132 MB), nontemporal y.
__global__ void __launch_bounds__(256, 8)
ts_coop(const float* __restrict__ x, const int* __restrict__ mask,
        float4* __restrict__ loc4,
        const int* __restrict__ prev_count, const float* __restrict__ prev_mean,
        const float* __restrict__ prev_var,
        const float* __restrict__ weight, const float* __restrict__ bias,
        float* __restrict__ y, float* __restrict__ out_count,
        float* __restrict__ out_mean, float* __restrict__ out_var,
        int B, int L, int D, int NC, int CPB, float inv_gs)
{
    __shared__ float s_gm[MAXCPB][NGROUPS][CHUNK];
    __shared__ float s_mean[NGROUPS][CHUNK + 1];   // +1 pad vs stride-8 writes
    __shared__ float s_rstd[NGROUPS][CHUNK + 1];

    const int tid = threadIdx.x;
    const int g   = tid / TPG;
    const int k   = tid & (TPG - 1);
    const bool leader = (k == 0);
    const int BNC = B * NC;
    const int gc0 = blockIdx.x * CPB;

    // --- phase 1: per owned chunk, group means + chunk Welford aggregate ---
    for (int i = 0; i < CPB; ++i) {
        const int gc = gc0 + i;
        if (gc >= BNC) break;                    // block-uniform
        const int b  = gc / NC, c = gc % NC;
        const int t0 = c * CHUNK;
        const int t1 = min(t0 + CHUNK, L);
        const float* xb = x + (size_t)b * L * D + tid * 8;
        const int*   mb = mask + (size_t)b * L;

        float n = 0.f, mean = 0.f, m2 = 0.f;
        #pragma unroll
        for (int t = t0; t < t1; ++t) {
            const float4* p = (const float4*)(xb + (size_t)t * D);
            float4 v0 = p[0], v1 = p[1];
            float s = sum8(v0, v1);
            s += __shfl_xor(s, 1, 64);
            s += __shfl_xor(s, 2, 64);
            s += __shfl_xor(s, 4, 64);
            s += __shfl_xor(s, 8, 64);
            float gmv = s * inv_gs;
            if (leader) s_gm[i][g][t - t0] = gmv;
            if (mb[t]) {                         // wave-uniform branch
                n += 1.f;
                float d = gmv - mean;
                mean += __fdividef(d, n);
                m2 = fmaf(d, gmv - mean, m2);
            }
        }
        if (leader) {                            // publish (agent scope, R3-proven)
            float* slot = (float*)&loc4[((size_t)b * NGROUPS + g) * NC + c];
            __hip_atomic_store(slot + 0, n,    __ATOMIC_RELAXED, __HIP_MEMORY_SCOPE_AGENT);
            __hip_atomic_store(slot + 1, mean, __ATOMIC_RELAXED, __HIP_MEMORY_SCOPE_AGENT);
            __hip_atomic_store(slot + 2, m2,   __ATOMIC_RELAXED, __HIP_MEMORY_SCOPE_AGENT);
        }
    }

    cg::this_grid().sync();   // release/acquire across XCDs (R3-proven)

    // hoist weight/bias (reused across owned chunks)
    const float4* wp = (const float4*)(weight + tid * 8);
    const float4* hp = (const float4*)(bias + tid * 8);
    float4 w0 = wp[0], w1 = wp[1];
    float4 h0 = hp[0], h1 = hp[1];
    w0.x += 1.f; w0.y += 1.f; w0.z += 1.f; w0.w += 1.f;
    w1.x += 1.f; w1.y += 1.f; w1.z += 1.f; w1.w += 1.f;

    // --- phases 2-4 per owned chunk ---
    for (int i = 0; i < CPB; ++i) {
        const int gc = gc0 + i;
        if (gc >= BNC) break;                    // block-uniform
        const int b  = gc / NC, c = gc % NC;
        const int chain = b * NGROUPS + g;
        const int t0 = c * CHUNK;
        const int jmax = min(CHUNK, L - t0);

        // phase 2: predecessor merge (L2 hits), lanes strided over chunks
        float n = 0.f, mean = 0.f, m2 = 0.f;
        const float* lrow = (const float*)(loc4 + (size_t)chain * NC);
        for (int cp = k; cp < c; cp += TPG) {
            const float* slot = lrow + (size_t)cp * 4;
            float vn = __hip_atomic_load(slot + 0, __ATOMIC_RELAXED, __HIP_MEMORY_SCOPE_AGENT);
            float vm = __hip_atomic_load(slot + 1, __ATOMIC_RELAXED, __HIP_MEMORY_SCOPE_AGENT);
            float v2 = __hip_atomic_load(slot + 2, __ATOMIC_RELAXED, __HIP_MEMORY_SCOPE_AGENT);
            wmerge(n, mean, m2, vn, vm, v2);
        }
        #pragma unroll
        for (int o = 1; o < TPG; o <<= 1) {
            float on = __shfl_xor(n, o, 64);
            float om = __shfl_xor(mean, o, 64);
            float o2 = __shfl_xor(m2, o, 64);
            wmerge(n, mean, m2, on, om, o2);
        }
        // merge prev-chain state (prev ∪ chunk-union; commutative)
        float pn = (float)prev_count[b];
        float pm = prev_mean[chain];
        float p2 = prev_var[chain] * fmaxf(pn, 1.0f);
        wmerge(pn, pm, p2, n, mean, m2);

        // phase 3: leader replays per-timestep states into LDS (from s_gm)
        if (leader) {
            const int* mrow = mask + (size_t)b * L + t0;
            float rn = pn, rm = pm, r2 = p2;
            float var = fmaxf(__fdividef(r2, fmaxf(rn, 1.f)), VFLOOR);
            #pragma unroll
            for (int j = 0; j < jmax; ++j) {
                float gmv = s_gm[i][g][j];
                if (mrow[j]) {
                    rn += 1.f;
                    float d = gmv - rm;
                    rm += __fdividef(d, rn);
                    r2 = fmaf(d, gmv - rm, r2);
                }
                var = fmaxf(__fdividef(r2, fmaxf(rn, 1.f)), VFLOOR);
                s_mean[g][j] = rm;
                s_rstd[g][j] = rsqrtf(var + EPS_F);
            }
            if (c == NC - 1) {
                out_mean[chain] = rm;
                out_var[chain]  = var;
                if (g == 0) out_count[b] = rn;
            }
        }
        __syncthreads();

        // phase 4: normalize the chunk (x re-read = L3 hit), nontemporal y
        const float* xb = x + ((size_t)b * L + t0) * D + tid * 8;
        float*       yb = y + ((size_t)b * L + t0) * D + tid * 8;
        #pragma unroll 2
        for (int j = 0; j < jmax; ++j) {
            float m_ = s_mean[g][j];             // broadcast within 16-lane cohort
            float r_ = s_rstd[g][j];
            const float4* p = (const float4*)(xb + (size_t)j * D);
            float4 v0 = p[0], v1 = p[1];
            v4f o0, o1;
            o0.x = fmaf((v0.x - m_) * r_, w0.x, h0.x);
            o0.y = fmaf((v0.y - m_) * r_, w0.y, h0.y);
            o0.z = fmaf((v0.z - m_) * r_, w0.z, h0.z);
            o0.w = fmaf((v0.w - m_) * r_, w0.w, h0.w);
            o1.x = fmaf((v1.x - m_) * r_, w1.x, h1.x);
            o1.y = fmaf((v1.y - m_) * r_, w1.y, h1.y);
            o1.z = fmaf((v1.z - m_) * r_, w1.z, h1.z);
            o1.w = fmaf((v1.w - m_) * r_, w1.w, h1.w);
            v4f* q = (v4f*)(yb + (size_t)j * D);
            __builtin_nontemporal_store(o0, q);  // y never re-read: keep L3 for x
            __builtin_nontemporal_store(o1, q + 1);
        }
        __syncthreads();                         // protect s_mean before next iter
    }
}

extern "C" void kernel_launch(void* const* d_in, const int* in_sizes, int n_in,
                              void* d_out, int out_size, void* d_ws, size_t ws_size,
                              hipStream_t stream) {
    const float* x          = (const float*)d_in[0];
    const int*   prev_count = (const int*)d_in[1];
    const float* prev_mean  = (const float*)d_in[2];
    const float* prev_var   = (const float*)d_in[3];
    const int*   mask       = (const int*)d_in[4];     // bool stored as int32
    const float* weight     = (const float*)d_in[5];
    const float* bias       = (const float*)d_in[6];

    const int B  = in_sizes[1];
    const int D  = in_sizes[5];
    const int L  = in_sizes[4] / B;
    const int NC = (L + CHUNK - 1) / CHUNK;     // 512
    const int BG = B * NGROUPS;
    const float inv_gs = (float)NGROUPS / (float)D;

    float* out = (float*)d_out;
    const size_t yN = (size_t)B * L * D;
    float* out_y     = out;
    float* out_count = out + yN;
    float* out_mean  = out + yN + B;
    float* out_var   = out + yN + B + BG;

    // workspace: loc4 [B*G*NC] float4 (512 KB)
    float4* loc4 = (float4*)d_ws;

    // max co-resident grid (cached): occupancy query x CU count. Runtime also
    // re-validates at launch (error, not hang, on violation). Fallback = 512
    // blocks (R3-proven co-resident).
    static int s_maxGrid = 0;
    if (s_maxGrid == 0) {
        int nb = 0;
        if (hipOccupancyMaxActiveBlocksPerMultiprocessor(&nb, ts_coop, 256, 0)
                != hipSuccess || nb <= 0) nb = 2;
        int dev = 0, cu = 0;
        if (hipGetDevice(&dev) != hipSuccess) dev = 0;
        if (hipDeviceGetAttribute(&cu, hipDeviceAttributeMultiprocessorCount, dev)
                != hipSuccess || cu <= 0) cu = 256;
        s_maxGrid = nb * cu;
        if (s_maxGrid < 128) s_maxGrid = 128;   // MAXCPB=16 covers 2048 chunks
    }

    const int BNC = B * NC;                     // 2048
    int CPB = (BNC + s_maxGrid - 1) / s_maxGrid;
    if (CPB > MAXCPB) CPB = MAXCPB;
    const int grid = (BNC + CPB - 1) / CPB;

    void* args[] = {
        (void*)&x, (void*)&mask, (void*)&loc4,
        (void*)&prev_count, (void*)&prev_mean, (void*)&prev_var,
        (void*)&weight, (void*)&bias,
        (void*)&out_y, (void*)&out_count, (void*)&out_mean, (void*)&out_var,
        (void*)&B, (void*)&L, (void*)&D, (void*)&NC, (void*)&CPB, (void*)&inv_gs
    };

    (void)hipLaunchCooperativeKernel((const void*)ts_coop,
                                     dim3(grid), dim3(D / 8),
                                     args, 0, stream);
}

// Round 6
// 380.120 us; speedup vs baseline: 1.1351x; 1.1351x over previous
//
#include <hip/hip_runtime.h>

#define NGROUPS 16          // G
#define TPG     16          // threads (lanes) per group in the reduce = 16
#define CHUNK   8           // timesteps per chunk; x held in regs (16 float4)
#define EPS_F   1e-5f
#define VFLOOR  1e-6f

typedef float v4f __attribute__((ext_vector_type(4)));   // native vec for nontemporal store

__device__ __forceinline__ float sum8(const float4& a, const float4& b) {
    return ((a.x + a.y) + (a.z + a.w)) + ((b.x + b.y) + (b.z + b.w));
}

// Chan/Welford set-union merge: (na,ma,m2a) ∪= (nb,mb,m2b). Commutative.
__device__ __forceinline__ void wmerge(float& na, float& ma, float& m2a,
                                       float nb, float mb, float m2b) {
    if (nb > 0.f) {
        float nn = na + nb;
        float d  = mb - ma;
        float r  = nb / nn;
        ma  = fmaf(d, r, ma);
        m2a = m2a + m2b + d * d * (na * r);
        na  = nn;
    }
}

// ---------- single-pass decoupled-lookback scan (ticket-ordered, deadlock-free) ----------
// Ticket remap: block -> chunk in DISPATCH order, so a block only spins on
// flags of already-running blocks, and locals are published with no waiting
// -> forward progress with ANY residency (this fixes R2's hang; no grid.sync,
// which R5 proved costs 3x). x is read ONCE from HBM and held in registers
// across the wait (no L3 re-read). Lookback merges ALL predecessor locals
// (16 lanes parallel, <=32 dependent rounds) -- no serial inclusive chain.
__global__ void __launch_bounds__(256, 4)
ts_scan(const float* __restrict__ x, const int* __restrict__ mask,
        int* __restrict__ ticket, int* __restrict__ flags, float4* __restrict__ loc4,
        const int* __restrict__ prev_count, const float* __restrict__ prev_mean,
        const float* __restrict__ prev_var,
        const float* __restrict__ weight, const float* __restrict__ bias,
        float* __restrict__ y, float* __restrict__ out_count,
        float* __restrict__ out_mean, float* __restrict__ out_var,
        int B, int L, int D, int NC, float inv_gs)
{
    __shared__ int   s_gc;
    __shared__ float s_gm[NGROUPS][CHUNK];
    __shared__ float s_mean[NGROUPS][CHUNK + 1];   // +1 pad vs stride-8 writes
    __shared__ float s_rstd[NGROUPS][CHUNK + 1];

    const int tid = threadIdx.x;
    const int g   = tid / TPG;
    const int k   = tid & (TPG - 1);
    const bool leader = (k == 0);

    // --- ticket: dispatch-order chunk assignment ---
    if (tid == 0)
        s_gc = __hip_atomic_fetch_add(ticket, 1, __ATOMIC_RELAXED, __HIP_MEMORY_SCOPE_AGENT);
    __syncthreads();
    const int gc = s_gc;
    const int b  = gc / NC, c = gc % NC;
    const int chain = b * NGROUPS + g;
    const int t0 = c * CHUNK;

    // --- phase 1: read x (only HBM read, kept in regs), gm + chunk Welford ---
    const float* xb   = x + ((size_t)b * L + t0) * D + tid * 8;
    const int*   mrow = mask + (size_t)b * L + t0;

    float4 xv0[CHUNK], xv1[CHUNK];
    float n = 0.f, mean = 0.f, m2 = 0.f;
    #pragma unroll
    for (int j = 0; j < CHUNK; ++j) {
        const bool inb = (t0 + j) < L;           // block-uniform (true for L%8==0)
        float4 v0 = make_float4(0.f,0.f,0.f,0.f), v1 = v0;
        if (inb) {
            const float4* p = (const float4*)(xb + (size_t)j * D);
            v0 = p[0]; v1 = p[1];
        }
        xv0[j] = v0; xv1[j] = v1;
        float s = sum8(v0, v1);
        s += __shfl_xor(s, 1, 64);
        s += __shfl_xor(s, 2, 64);
        s += __shfl_xor(s, 4, 64);
        s += __shfl_xor(s, 8, 64);
        float gmv = s * inv_gs;
        if (leader) s_gm[g][j] = gmv;
        if (inb && mrow[j]) {                    // wave-uniform branch
            n += 1.f;
            float d = gmv - mean;
            mean += __fdividef(d, n);
            m2 = fmaf(d, gmv - mean, m2);
        }
    }

    // --- publish local aggregate (R3-proven pattern: relaxed-agent payload,
    //     __syncthreads drains vmcnt, then release flag) ---
    if (leader) {
        float* slot = (float*)&loc4[(size_t)chain * NC + c];
        __hip_atomic_store(slot + 0, n,    __ATOMIC_RELAXED, __HIP_MEMORY_SCOPE_AGENT);
        __hip_atomic_store(slot + 1, mean, __ATOMIC_RELAXED, __HIP_MEMORY_SCOPE_AGENT);
        __hip_atomic_store(slot + 2, m2,   __ATOMIC_RELAXED, __HIP_MEMORY_SCOPE_AGENT);
    }
    __syncthreads();
    if (tid == 0)
        __hip_atomic_store(&flags[gc], 1, __ATOMIC_RELEASE, __HIP_MEMORY_SCOPE_AGENT);

    // --- phase 2: lookback over ALL predecessor locals (lanes strided) ---
    float cn = 0.f, cm = 0.f, c2 = 0.f;
    {
        const float* lrow = (const float*)(loc4 + (size_t)chain * NC);
        const int fbase = b * NC;
        for (int cp = k; cp < c; cp += TPG) {
            const int* f = &flags[fbase + cp];
            while (__hip_atomic_load(f, __ATOMIC_RELAXED, __HIP_MEMORY_SCOPE_AGENT) == 0)
                __builtin_amdgcn_s_sleep(1);
            asm volatile("" ::: "memory");       // keep payload loads after spin exit
            const float* slot = lrow + (size_t)cp * 4;
            float vn = __hip_atomic_load(slot + 0, __ATOMIC_RELAXED, __HIP_MEMORY_SCOPE_AGENT);
            float vm = __hip_atomic_load(slot + 1, __ATOMIC_RELAXED, __HIP_MEMORY_SCOPE_AGENT);
            float v2 = __hip_atomic_load(slot + 2, __ATOMIC_RELAXED, __HIP_MEMORY_SCOPE_AGENT);
            wmerge(cn, cm, c2, vn, vm, v2);
        }
    }
    // shfl tree over the 16 lanes of this group (fixed order -> deterministic)
    #pragma unroll
    for (int o = 1; o < TPG; o <<= 1) {
        float on = __shfl_xor(cn, o, 64);
        float om = __shfl_xor(cm, o, 64);
        float o2 = __shfl_xor(c2, o, 64);
        wmerge(cn, cm, c2, on, om, o2);
    }
    // merge prev-chain state (prev ∪ predecessor-union; commutative)
    float pn = (float)prev_count[b];
    float pm = prev_mean[chain];
    float p2 = prev_var[chain] * fmaxf(pn, 1.0f);
    wmerge(pn, pm, p2, cn, cm, c2);

    // --- phase 3: leader replays per-timestep states into LDS ---
    const int jmax = min(CHUNK, L - t0);
    if (leader) {
        float rn = pn, rm = pm, r2 = p2;
        float var = fmaxf(__fdividef(r2, fmaxf(rn, 1.f)), VFLOOR);
        #pragma unroll
        for (int j = 0; j < CHUNK; ++j) {
            if (j < jmax) {
                float gmv = s_gm[g][j];
                if (mrow[j]) {
                    rn += 1.f;
                    float d = gmv - rm;
                    rm += __fdividef(d, rn);
                    r2 = fmaf(d, gmv - rm, r2);
                }
                var = fmaxf(__fdividef(r2, fmaxf(rn, 1.f)), VFLOOR);
                s_mean[g][j] = rm;
                s_rstd[g][j] = rsqrtf(var + EPS_F);
            }
        }
        if (c == NC - 1) {
            out_mean[chain] = rm;
            out_var[chain]  = var;
            if (g == 0) out_count[b] = rn;
        }
    }

    // weight/bias loads here: overlap leaders' replay, short live range (no spill)
    const float4* wp = (const float4*)(weight + tid * 8);
    const float4* hp = (const float4*)(bias + tid * 8);
    float4 w0 = wp[0], w1 = wp[1];
    float4 h0 = hp[0], h1 = hp[1];
    w0.x += 1.f; w0.y += 1.f; w0.z += 1.f; w0.w += 1.f;
    w1.x += 1.f; w1.y += 1.f; w1.z += 1.f; w1.w += 1.f;

    __syncthreads();

    // --- phase 4: normalize from registers, nontemporal y store ---
    float* yb = y + ((size_t)b * L + t0) * D + tid * 8;
    #pragma unroll
    for (int j = 0; j < CHUNK; ++j) {
        if ((t0 + j) < L) {
            float m_ = s_mean[g][j];             // broadcast within 16-lane cohort
            float r_ = s_rstd[g][j];
            float4 v0 = xv0[j], v1 = xv1[j];
            v4f o0, o1;
            o0.x = fmaf((v0.x - m_) * r_, w0.x, h0.x);
            o0.y = fmaf((v0.y - m_) * r_, w0.y, h0.y);
            o0.z = fmaf((v0.z - m_) * r_, w0.z, h0.z);
            o0.w = fmaf((v0.w - m_) * r_, w0.w, h0.w);
            o1.x = fmaf((v1.x - m_) * r_, w1.x, h1.x);
            o1.y = fmaf((v1.y - m_) * r_, w1.y, h1.y);
            o1.z = fmaf((v1.z - m_) * r_, w1.z, h1.z);
            o1.w = fmaf((v1.w - m_) * r_, w1.w, h1.w);
            v4f* q = (v4f*)(yb + (size_t)j * D);
            __builtin_nontemporal_store(o0, q);  // y never re-read
            __builtin_nontemporal_store(o1, q + 1);
        }
    }
}

extern "C" void kernel_launch(void* const* d_in, const int* in_sizes, int n_in,
                              void* d_out, int out_size, void* d_ws, size_t ws_size,
                              hipStream_t stream) {
    const float* x          = (const float*)d_in[0];
    const int*   prev_count = (const int*)d_in[1];
    const float* prev_mean  = (const float*)d_in[2];
    const float* prev_var   = (const float*)d_in[3];
    const int*   mask       = (const int*)d_in[4];     // bool stored as int32
    const float* weight     = (const float*)d_in[5];
    const float* bias       = (const float*)d_in[6];

    const int B  = in_sizes[1];
    const int D  = in_sizes[5];
    const int L  = in_sizes[4] / B;
    const int NC = (L + CHUNK - 1) / CHUNK;     // 512
    const int BG = B * NGROUPS;
    const int BNC = B * NC;                     // 2048
    const float inv_gs = (float)NGROUPS / (float)D;

    float* out = (float*)d_out;
    const size_t yN = (size_t)B * L * D;
    float* out_y     = out;
    float* out_count = out + yN;
    float* out_mean  = out + yN + B;
    float* out_var   = out + yN + B + BG;

    // workspace layout: [ticket int][flags BNC ints] (zeroed each launch; the
    // harness poisons d_ws, so flags MUST be cleared), then loc4 [B*G*NC] float4.
    int* ticket = (int*)d_ws;
    int* flags  = (int*)d_ws + 64;                      // 256 B offset
    const size_t ctl = ((256 + (size_t)BNC * 4) + 255) & ~(size_t)255;
    float4* loc4 = (float4*)((char*)d_ws + ctl);

    (void)hipMemsetAsync(d_ws, 0, 256 + (size_t)BNC * 4, stream);   // ~8.4 KB

    ts_scan<<<BNC, dim3(D / 8), 0, stream>>>(x, mask, ticket, flags, loc4,
                                             prev_count, prev_mean, prev_var,
                                             weight, bias,
                                             out_y, out_count, out_mean, out_var,
                                             B, L, D, NC, inv_gs);
}

// Round 7
// 288.078 us; speedup vs baseline: 1.4978x; 1.3195x over previous
//
#include <hip/hip_runtime.h>

#define NGROUPS 16          // G
#define TPG     16          // lanes per group cohort (gs=128 = 16 lanes x 8 floats)
#define CHUNK   8           // timesteps per block in K1/K3
#define EPS_F   1e-5f
#define VFLOOR  1e-6f

typedef float v4f __attribute__((ext_vector_type(4)));   // native vec for nontemporal store

__device__ __forceinline__ float sum8(const float4& a, const float4& b) {
    return ((a.x + a.y) + (a.z + a.w)) + ((b.x + b.y) + (b.z + b.w));
}

// Chan/Welford set-union merge: (na,ma,m2a) ∪= (nb,mb,m2b). Commutative, associative.
__device__ __forceinline__ void wmerge(float& na, float& ma, float& m2a,
                                       float nb, float mb, float m2b) {
    if (nb > 0.f) {
        float nn = na + nb;
        float d  = mb - ma;
        float r  = nb / nn;
        ma  = fmaf(d, r, ma);
        m2a = m2a + m2b + d * d * (na * r);
        na  = nn;
    }
}

// ---------------- K1: group means only (pure streaming reduce) ----------------
// grid = B*NC = 2048 (8 blocks/CU), block = 256. The only HBM read of x.
// gm layout: [b][g][t] (contiguous per chain for K2's coalesced scan reads).
// No mask, no Welford, no aggregates here -- all scan work hoisted to K2.
__global__ void __launch_bounds__(256)
k_gm(const float* __restrict__ x, float* __restrict__ gm,
     int B, int L, int D, int NC, float inv_gs)
{
    const int b   = blockIdx.x / NC;
    const int c   = blockIdx.x % NC;
    const int tid = threadIdx.x;
    const int g   = tid / TPG;
    const bool leader = (tid & (TPG - 1)) == 0;
    const int t0  = c * CHUNK;
    const int t1  = min(t0 + CHUNK, L);

    const float* xb = x + (size_t)b * L * D + tid * 8;
    float* gmr = gm + ((size_t)b * NGROUPS + g) * L;

    #pragma unroll
    for (int t = t0; t < t1; ++t) {
        const float4* p = (const float4*)(xb + (size_t)t * D);
        float4 v0 = p[0], v1 = p[1];
        float s = sum8(v0, v1);
        s += __shfl_xor(s, 1, 64);
        s += __shfl_xor(s, 2, 64);
        s += __shfl_xor(s, 4, 64);
        s += __shfl_xor(s, 8, 64);
        if (leader) gmr[t] = s * inv_gs;
    }
}

// ---------------- K2: per-chain scan + replay (tiny: 64 blocks) ----------------
// block = 256 threads = one chain (b,g). Thread i owns timesteps [i*TPT,(i+1)*TPT).
// 1. local masked-Welford aggregate over own range (gm reads: 64 B/thread, coalesced)
// 2. 8-round LDS Hillis-Steele inclusive scan over 256 aggregates (wmerge)
// 3. exclusive prefix = s[i-1]; merge prev-chain state
// 4. replay own range, writing (mean, rstd) float2 -> ms[b][g][t]
// Removes ALL scan/lookback/replay work from the BW-heavy K3.
__global__ void __launch_bounds__(256)
k_scan(const float* __restrict__ gm, const int* __restrict__ mask,
       const int* __restrict__ prev_count, const float* __restrict__ prev_mean,
       const float* __restrict__ prev_var,
       float2* __restrict__ ms, float* __restrict__ out_count,
       float* __restrict__ out_mean, float* __restrict__ out_var,
       int B, int L)
{
    __shared__ float sn[256], sm[256], s2[256];

    const int chain = blockIdx.x;            // 0 .. B*G-1
    const int b   = chain / NGROUPS;
    const int g   = chain - b * NGROUPS;
    const int tid = threadIdx.x;
    const int TPT = (L + 255) / 256;         // 16 for L=4096
    const int t0  = tid * TPT;
    const int t1  = min(t0 + TPT, L);

    const float* gmr = gm + (size_t)chain * L;
    const int*   mr  = mask + (size_t)b * L;

    // 1. local aggregate (streaming Welford over own timesteps)
    float n = 0.f, m = 0.f, m2 = 0.f;
    for (int t = t0; t < t1; ++t) {
        if (mr[t]) {
            n += 1.f;
            float gmv = gmr[t];
            float d = gmv - m;
            m += __fdividef(d, n);
            m2 = fmaf(d, gmv - m, m2);
        }
    }

    // 2. inclusive Hillis-Steele scan in LDS
    float cn = n, cm = m, c2 = m2;
    sn[tid] = cn; sm[tid] = cm; s2[tid] = c2;
    __syncthreads();
    #pragma unroll
    for (int o = 1; o < 256; o <<= 1) {
        float tn = 0.f, tm = 0.f, t2 = 0.f;
        const bool h = (tid >= o);
        if (h) { tn = sn[tid - o]; tm = sm[tid - o]; t2 = s2[tid - o]; }
        __syncthreads();
        if (h) { wmerge(tn, tm, t2, cn, cm, c2); cn = tn; cm = tm; c2 = t2; }
        sn[tid] = cn; sm[tid] = cm; s2[tid] = c2;
        __syncthreads();
    }

    // 3. exclusive prefix + prev-chain state
    float en = 0.f, em = 0.f, e2 = 0.f;
    if (tid > 0) { en = sn[tid - 1]; em = sm[tid - 1]; e2 = s2[tid - 1]; }
    float pn = (float)prev_count[b];
    float pm = prev_mean[chain];
    float p2 = prev_var[chain] * fmaxf(pn, 1.0f);
    wmerge(pn, pm, p2, en, em, e2);          // state just before t0

    // 4. replay own range -> (mean, rstd)
    float2* msr = ms + (size_t)chain * L;
    float rn = pn, rm = pm, r2 = p2;
    float var = fmaxf(__fdividef(r2, fmaxf(rn, 1.f)), VFLOOR);
    for (int t = t0; t < t1; ++t) {
        float gmv = gmr[t];
        if (mr[t]) {
            rn += 1.f;
            float d = gmv - rm;
            rm += __fdividef(d, rn);
            r2 = fmaf(d, gmv - rm, r2);
        }
        var = fmaxf(__fdividef(r2, fmaxf(rn, 1.f)), VFLOOR);
        msr[t] = make_float2(rm, rsqrtf(var + EPS_F));
    }
    if (t0 <= L - 1 && L - 1 < t1) {         // owner of the final timestep
        out_mean[chain] = rm;
        out_var[chain]  = var;
        if (g == 0) out_count[b] = rn;
    }
}

// ---------------- K3: pure elementwise normalize ----------------
// grid = B*NC = 2048, block = 256. No LDS, no syncthreads, no divergence.
// ms float2 load is an 8 B broadcast within each 16-lane cohort (L2-hot, 2 MB).
// x re-read = L3 hit (proven R3/R6: FETCH stays ~x-size). y = nontemporal.
__global__ void __launch_bounds__(256)
k_norm(const float* __restrict__ x, const float2* __restrict__ ms,
       const float* __restrict__ weight, const float* __restrict__ bias,
       float* __restrict__ y, int B, int L, int D, int NC)
{
    const int b   = blockIdx.x / NC;
    const int c   = blockIdx.x % NC;
    const int tid = threadIdx.x;
    const int g   = tid / TPG;
    const int t0  = c * CHUNK;
    const int jmax = min(CHUNK, L - t0);

    const float4* wp = (const float4*)(weight + tid * 8);
    const float4* hp = (const float4*)(bias + tid * 8);
    float4 w0 = wp[0], w1 = wp[1];
    float4 h0 = hp[0], h1 = hp[1];
    w0.x += 1.f; w0.y += 1.f; w0.z += 1.f; w0.w += 1.f;
    w1.x += 1.f; w1.y += 1.f; w1.z += 1.f; w1.w += 1.f;

    const float2* msr = ms + ((size_t)b * NGROUPS + g) * L + t0;
    const float*  xb  = x + ((size_t)b * L + t0) * D + tid * 8;
    float*        yb  = y + ((size_t)b * L + t0) * D + tid * 8;

    // prefetch the chunk's stats (independent 8B loads, overlap with x loads)
    float2 st[CHUNK];
    #pragma unroll
    for (int j = 0; j < CHUNK; ++j)
        if (j < jmax) st[j] = msr[j];

    #pragma unroll
    for (int j = 0; j < CHUNK; ++j) {
        if (j < jmax) {
            const float m_ = st[j].x;
            const float r_ = st[j].y;
            const float4* p = (const float4*)(xb + (size_t)j * D);
            float4 v0 = p[0], v1 = p[1];
            v4f o0, o1;
            o0.x = fmaf((v0.x - m_) * r_, w0.x, h0.x);
            o0.y = fmaf((v0.y - m_) * r_, w0.y, h0.y);
            o0.z = fmaf((v0.z - m_) * r_, w0.z, h0.z);
            o0.w = fmaf((v0.w - m_) * r_, w0.w, h0.w);
            o1.x = fmaf((v1.x - m_) * r_, w1.x, h1.x);
            o1.y = fmaf((v1.y - m_) * r_, w1.y, h1.y);
            o1.z = fmaf((v1.z - m_) * r_, w1.z, h1.z);
            o1.w = fmaf((v1.w - m_) * r_, w1.w, h1.w);
            v4f* q = (v4f*)(yb + (size_t)j * D);
            __builtin_nontemporal_store(o0, q);   // y never re-read
            __builtin_nontemporal_store(o1, q + 1);
        }
    }
}

extern "C" void kernel_launch(void* const* d_in, const int* in_sizes, int n_in,
                              void* d_out, int out_size, void* d_ws, size_t ws_size,
                              hipStream_t stream) {
    const float* x          = (const float*)d_in[0];
    const int*   prev_count = (const int*)d_in[1];
    const float* prev_mean  = (const float*)d_in[2];
    const float* prev_var   = (const float*)d_in[3];
    const int*   mask       = (const int*)d_in[4];     // bool stored as int32
    const float* weight     = (const float*)d_in[5];
    const float* bias       = (const float*)d_in[6];

    const int B  = in_sizes[1];
    const int D  = in_sizes[5];
    const int L  = in_sizes[4] / B;
    const int NC = (L + CHUNK - 1) / CHUNK;     // 512
    const int BG = B * NGROUPS;                 // 64
    const float inv_gs = (float)NGROUPS / (float)D;

    float* out = (float*)d_out;
    const size_t yN = (size_t)B * L * D;
    float* out_y     = out;
    float* out_count = out + yN;
    float* out_mean  = out + yN + B;
    float* out_var   = out + yN + B + BG;

    // workspace: gm [B*G*L] floats (1 MB), ms [B*G*L] float2 (2 MB)
    float* gm = (float*)d_ws;
    const size_t gmN = (size_t)BG * L;
    float2* ms = (float2*)(gm + gmN);

    dim3 blk(D / 8);   // 256

    k_gm  <<<B * NC, blk, 0, stream>>>(x, gm, B, L, D, NC, inv_gs);

    k_scan<<<BG, 256, 0, stream>>>(gm, mask, prev_count, prev_mean, prev_var,
                                   ms, out_count, out_mean, out_var, B, L);

    k_norm<<<B * NC, blk, 0, stream>>>(x, ms, weight, bias, out_y, B, L, D, NC);
}